// Round 1
// baseline (1471.130 us; speedup 1.0000x reference)
//
#include <hip/hip_runtime.h>
#include <stdint.h>

// SparseDecoder: 4-layer masked MLP forward.
//   x:[64,512] fp32; layer i: K=SIZES[i] -> N=SIZES[i+1]
//   z_i = x @ (W_i * mask_i)^T + b_i ; relu between layers (applied on READ
//   by the next layer's GEMM; each GEMM stores pre-activation z).
//
// ROUND THEORY: prior LDS-staged version ran at ~1.07 TB/s (17% of HBM).
// With BATCH=64 the full W-reuse fits in ONE wave's MFMA fragments, so LDS
// staging + per-chunk __syncthreads (vmcnt(0) drains) were pure overhead.
// This version: register-fragment streaming GEMM. One 64-thread block
// (= one wave) owns a 64n x 64batch output tile and streams W/mask straight
// HBM -> VGPR -> MFMA with no LDS and no barriers. W+mask read exactly once
// device-wide; x (0.125-2 MB) re-read from per-XCD L2.
//
// MASK DTYPE: runtime probe detects int32 vs u8 bool layout (see probe).
// Compute: bf16 MFMA 16x16x32, fp32 accumulate (error ~5e-5 vs 9.2e-4
// threshold — verified in earlier rounds). atomicAdd K-split partials into
// bias-initialized z buffers.

typedef short bf16x8 __attribute__((ext_vector_type(8)));   // 8 bf16 (4 VGPRs)
typedef float f32x4  __attribute__((ext_vector_type(4)));   // 4 fp32 acc

__device__ __forceinline__ unsigned short f2bf(float f) {
    // round-to-nearest-even fp32 -> bf16 (finite inputs)
    unsigned int u = __float_as_uint(f);
    return (unsigned short)((u + 0x7FFFu + ((u >> 16) & 1u)) >> 16);
}

__device__ __forceinline__ unsigned int bfpair(float lo, float hi) {
    return (unsigned int)f2bf(lo) | ((unsigned int)f2bf(hi) << 16);
}

__device__ __forceinline__ bf16x8 pack8(const float4& a, const float4& b) {
    union { unsigned int u[4]; bf16x8 v; } r;
    r.u[0] = bfpair(a.x, a.y);
    r.u[1] = bfpair(a.z, a.w);
    r.u[2] = bfpair(b.x, b.y);
    r.u[3] = bfpair(b.z, b.w);
    return r.v;
}

// Detect mask storage: writes flag=1 if masks are 1-byte bools, 0 if int32.
// Scans first 16 KB of mask0 (>=1MB under either layout, so always in
// bounds). int32 bools (0/1) have all upper 3 bytes zero; u8 bools have a
// nonzero upper byte in ~14% of words -> P(misdetect) ~ e^-631.
__global__ __launch_bounds__(256) void probe_mask_kind(
    const unsigned int* __restrict__ m, int* __restrict__ flag)
{
    __shared__ int s_any;
    if (threadIdx.x == 0) s_any = 0;
    __syncthreads();
    int any = 0;
    #pragma unroll
    for (int it = 0; it < 16; ++it) {
        unsigned int v = m[it * 256 + threadIdx.x];
        if (v & 0xFFFFFF00u) any = 1;
    }
    if (__any(any) && (threadIdx.x & 63) == 0) s_any = 1;
    __syncthreads();
    if (threadIdx.x == 0) flag[0] = s_any;   // 1 => u8 bools, 0 => int32
}

// Broadcast biases into all four z buffers in one launch.
// grid = (120, 64): 120*256 = 30720 = 2048+4096+8192+16384 cols, y = batch.
__global__ __launch_bounds__(256) void init_bias_all(
    const float* __restrict__ b0, const float* __restrict__ b1,
    const float* __restrict__ b2, const float* __restrict__ b3,
    float* __restrict__ z0, float* __restrict__ z1,
    float* __restrict__ z2, float* __restrict__ z3)
{
    int n = blockIdx.x * 256 + threadIdx.x;
    int b = blockIdx.y;
    if (n < 2048)             z0[(size_t)b * 2048  + n]           = b0[n];
    else if (n < 6144)        z1[(size_t)b * 4096  + (n - 2048)]  = b1[n - 2048];
    else if (n < 14336)       z2[(size_t)b * 8192  + (n - 6144)]  = b2[n - 6144];
    else                      z3[(size_t)b * 16384 + (n - 14336)] = b3[n - 14336];
}

// Inner streaming loop. MU8: mask dtype (1 = u8 bools, 0 = int32).
// RELU: apply relu to x on read (layers 1..3).
// Per 32-wide k-step, lane (lr,quad):
//   A-frag[ng]: W[n0+ng*16+lr][k+quad*8 .. +8]  (2x float4 + mask, select, cvt)
//   B-frag[bg]: x[bg*16+lr]  [k+quad*8 .. +8]  (2x float4, relu, cvt)
//   16 MFMA (4 ng x 4 bg) accumulate the 64x64 tile.
template <int MU8, int RELU>
__device__ __forceinline__ void gemm_loop(
    const float* __restrict__ X, const float* __restrict__ W,
    const unsigned char* __restrict__ Mk, const int* __restrict__ Mk32,
    int N, int K, int kbeg, int kend,
    int n0, int lr, int quad, f32x4 (&acc)[4][4])
{
    const size_t xoff = (size_t)lr * K + quad * 8;            // + bg*16*K + k
    const size_t woff = (size_t)(n0 + lr) * K + quad * 8;     // + ng*16*K + k

    #pragma unroll 1
    for (int k = kbeg; k < kend; k += 32) {
        // ---- B fragments: all 64 batches, this wave only ----
        bf16x8 bfr[4];
        #pragma unroll
        for (int bg = 0; bg < 4; ++bg) {
            const float* xp = X + xoff + (size_t)bg * 16 * K + k;
            float4 x0 = *(const float4*)xp;
            float4 x1 = *(const float4*)(xp + 4);
            if (RELU) {
                x0.x = fmaxf(x0.x, 0.f); x0.y = fmaxf(x0.y, 0.f);
                x0.z = fmaxf(x0.z, 0.f); x0.w = fmaxf(x0.w, 0.f);
                x1.x = fmaxf(x1.x, 0.f); x1.y = fmaxf(x1.y, 0.f);
                x1.z = fmaxf(x1.z, 0.f); x1.w = fmaxf(x1.w, 0.f);
            }
            bfr[bg] = pack8(x0, x1);
        }
        // ---- A fragments (masked W) + MFMA ----
        #pragma unroll
        for (int ng = 0; ng < 4; ++ng) {
            size_t e = woff + (size_t)ng * 16 * K + k;
            float4 w0 = *(const float4*)(W + e);
            float4 w1 = *(const float4*)(W + e + 4);
            if (MU8) {
                uint2 m8 = *(const uint2*)(Mk + e);   // 8 mask bytes
                w0.x = (m8.x & 0x000000FFu) ? w0.x : 0.f;
                w0.y = (m8.x & 0x0000FF00u) ? w0.y : 0.f;
                w0.z = (m8.x & 0x00FF0000u) ? w0.z : 0.f;
                w0.w = (m8.x & 0xFF000000u) ? w0.w : 0.f;
                w1.x = (m8.y & 0x000000FFu) ? w1.x : 0.f;
                w1.y = (m8.y & 0x0000FF00u) ? w1.y : 0.f;
                w1.z = (m8.y & 0x00FF0000u) ? w1.z : 0.f;
                w1.w = (m8.y & 0xFF000000u) ? w1.w : 0.f;
            } else {
                int4 m0 = *(const int4*)(Mk32 + e);
                int4 m1 = *(const int4*)(Mk32 + e + 4);
                w0.x = m0.x ? w0.x : 0.f;
                w0.y = m0.y ? w0.y : 0.f;
                w0.z = m0.z ? w0.z : 0.f;
                w0.w = m0.w ? w0.w : 0.f;
                w1.x = m1.x ? w1.x : 0.f;
                w1.y = m1.y ? w1.y : 0.f;
                w1.z = m1.z ? w1.z : 0.f;
                w1.w = m1.w ? w1.w : 0.f;
            }
            bf16x8 a = pack8(w0, w1);
            #pragma unroll
            for (int bg = 0; bg < 4; ++bg)
                acc[ng][bg] = __builtin_amdgcn_mfma_f32_16x16x32_bf16(
                    a, bfr[bg], acc[ng][bg], 0, 0, 0);
        }
    }
}

// One block = one wave (64 threads) computing a 64n x 64batch tile over
// K-range [y*kper, (y+1)*kper). No LDS, no __syncthreads.
__global__ __launch_bounds__(64, 2) void sparse_gemm_rf(
    const float* __restrict__ X,            // [64, K] pre-activation input
    const float* __restrict__ W,            // [N, K]
    const unsigned char* __restrict__ Mk,   // [N, K] mask (u8 or i32)
    const int* __restrict__ mflag,          // 1 => u8, 0 => i32
    float* __restrict__ Z,                  // [64, N], bias-initialized
    int N, int K, int kper, int relu_in)
{
    const int l    = threadIdx.x;  // 0..63
    const int lr   = l & 15;       // A: n-row within 16 / B: batch within 16
    const int quad = l >> 4;       // 0..3 -> k-subgroup of 8
    const int n0   = blockIdx.x * 64;
    const int kbeg = blockIdx.y * kper;
    const int kend = kbeg + kper;

    const int mask_u8 = *mflag;    // uniform
    const int* __restrict__ Mk32 = (const int*)Mk;

    f32x4 acc[4][4];
    #pragma unroll
    for (int i = 0; i < 4; ++i)
        #pragma unroll
        for (int j = 0; j < 4; ++j) acc[i][j] = (f32x4){0.f, 0.f, 0.f, 0.f};

    if (mask_u8) {
        if (relu_in) gemm_loop<1, 1>(X, W, Mk, Mk32, N, K, kbeg, kend, n0, lr, quad, acc);
        else         gemm_loop<1, 0>(X, W, Mk, Mk32, N, K, kbeg, kend, n0, lr, quad, acc);
    } else {
        if (relu_in) gemm_loop<0, 1>(X, W, Mk, Mk32, N, K, kbeg, kend, n0, lr, quad, acc);
        else         gemm_loop<0, 0>(X, W, Mk, Mk32, N, K, kbeg, kend, n0, lr, quad, acc);
    }

    // --- epilogue: D layout col=lane&15 (batch), row=quad*4+reg (n) ---
    #pragma unroll
    for (int ng = 0; ng < 4; ++ng) {
        #pragma unroll
        for (int bg = 0; bg < 4; ++bg) {
            int b = bg * 16 + lr;
            float* zp = Z + (size_t)b * N + n0 + ng * 16 + quad * 4;
            #pragma unroll
            for (int r = 0; r < 4; ++r) atomicAdd(&zp[r], acc[ng][bg][r]);
        }
    }
}

extern "C" void kernel_launch(void* const* d_in, const int* in_sizes, int n_in,
                              void* d_out, int out_size, void* d_ws, size_t ws_size,
                              hipStream_t stream) {
    // setup_inputs order: x, W0,b0,mask0, W1,b1,mask1, W2,b2,mask2, W3,b3,mask3
    const float* x  = (const float*)d_in[0];
    const float* W0 = (const float*)d_in[1];
    const float* b0 = (const float*)d_in[2];
    const unsigned char* m0 = (const unsigned char*)d_in[3];
    const float* W1 = (const float*)d_in[4];
    const float* b1 = (const float*)d_in[5];
    const unsigned char* m1 = (const unsigned char*)d_in[6];
    const float* W2 = (const float*)d_in[7];
    const float* b2 = (const float*)d_in[8];
    const unsigned char* m2 = (const unsigned char*)d_in[9];
    const float* W3 = (const float*)d_in[10];
    const float* b3 = (const float*)d_in[11];
    const unsigned char* m3 = (const unsigned char*)d_in[12];

    float* z0 = (float*)d_ws;              // [64, 2048]
    float* z1 = z0 + (size_t)64 * 2048;    // [64, 4096]
    float* z2 = z1 + (size_t)64 * 4096;    // [64, 8192]
    float* z3 = (float*)d_out;             // [64, 16384]
    int* mflag = (int*)(z2 + (size_t)64 * 8192);  // 1 int after z2 in ws

    probe_mask_kind<<<1, 256, 0, stream>>>((const unsigned int*)m0, mflag);
    init_bias_all<<<dim3(120, 64), 256, 0, stream>>>(b0, b1, b2, b3, z0, z1, z2, z3);

    // All layers: 64-thread blocks, grid (N/64, 8 K-splits).
    // layer 0: K=512,  N=2048 : grid (32, 8),  kper=64
    sparse_gemm_rf<<<dim3(32, 8),  64, 0, stream>>>(x,  W0, m0, mflag, z0, 2048,  512,   64, 0);
    // layer 1: K=2048, N=4096 : grid (64, 8),  kper=256
    sparse_gemm_rf<<<dim3(64, 8),  64, 0, stream>>>(z0, W1, m1, mflag, z1, 4096,  2048, 256, 1);
    // layer 2: K=4096, N=8192 : grid (128, 8), kper=512
    sparse_gemm_rf<<<dim3(128, 8), 64, 0, stream>>>(z1, W2, m2, mflag, z2, 8192,  4096, 512, 1);
    // layer 3: K=8192, N=16384: grid (256, 8), kper=1024
    sparse_gemm_rf<<<dim3(256, 8), 64, 0, stream>>>(z2, W3, m3, mflag, z3, 16384, 8192, 1024, 1);
}